// Round 5
// baseline (124.534 us; speedup 1.0000x reference)
//
#include <hip/hip_runtime.h>

// Backwarp (tfa.image.dense_image_warp):
// out[b,y,x,c] = bilinear(image, y - flow[b,y,x,0], x - flow[b,y,x,1])
// floors clamped to [0, size-2], alphas clamped to [0,1].

#define BB 4
#define HH 512
#define WW 512
#define CV 16        // float4 chunks per pixel (C=64)
#define NBLK 16384   // blocks; each covers 64 consecutive pixels (2 iters x 32)

typedef float f32x4 __attribute__((ext_vector_type(4)));
typedef float f32x2 __attribute__((ext_vector_type(2)));

__device__ __forceinline__ void warp_body(
    const f32x4* __restrict__ img4, f32x4* __restrict__ out4,
    long long p, int c8, f32x2 fl)
{
    int x = (int)(p & (WW - 1));
    long long t = p >> 9;
    int y = (int)(t & (HH - 1));
    int b = (int)(t >> 9);

    float qy = (float)y - fl.x;
    float qx = (float)x - fl.y;
    float fy = fminf(fmaxf(floorf(qy), 0.0f), (float)(HH - 2));
    float fx = fminf(fmaxf(floorf(qx), 0.0f), (float)(WW - 2));
    float ay = fminf(fmaxf(qy - fy, 0.0f), 1.0f);
    float ax = fminf(fmaxf(qx - fx, 0.0f), 1.0f);
    int y0 = (int)fy;
    int x0 = (int)fx;

    long long i00 = (((long long)b * HH + y0) * WW + x0) * CV + c8;
    long long i01 = i00 + CV;                  // x0+1
    long long i10 = i00 + (long long)WW * CV;  // y0+1
    long long i11 = i10 + CV;

    f32x4 tlA = img4[i00];  f32x4 tlB = img4[i00 + 8];
    f32x4 trA = img4[i01];  f32x4 trB = img4[i01 + 8];
    f32x4 blA = img4[i10];  f32x4 blB = img4[i10 + 8];
    f32x4 brA = img4[i11];  f32x4 brB = img4[i11 + 8];

    f32x4 topA = tlA + ax * (trA - tlA);
    f32x4 botA = blA + ax * (brA - blA);
    f32x4 rA   = topA + ay * (botA - topA);
    f32x4 topB = tlB + ax * (trB - tlB);
    f32x4 botB = blB + ax * (brB - blB);
    f32x4 rB   = topB + ay * (botB - topB);

    // A/B vs round 4: NORMAL stores (fill kernel proves 6.9 TB/s on this path)
    long long o = p * CV + c8;
    out4[o]     = rA;
    out4[o + 8] = rB;
}

__global__ __launch_bounds__(256) void backwarp_kernel(
    const float* __restrict__ image,
    const float* __restrict__ flow,
    float* __restrict__ out)
{
    // XCD-bijective swizzle: each XCD gets a contiguous 1/8 slab of the grid
    int bid = (int)blockIdx.x;
    int orig = (bid & 7) * (NBLK / 8) + (bid >> 3);

    long long pix_base = (long long)orig * 64;
    int c8 = (int)(threadIdx.x & 7);   // which pair of float4 chunks
    int pl = (int)(threadIdx.x >> 3);  // pixel lane 0..31
    long long p0 = pix_base + pl;
    long long p1 = pix_base + 32 + pl;

    // both flow loads issued up front: iter-1's flow latency hides under iter-0
    const f32x2* flow2 = (const f32x2*)flow;
    f32x2 fl0 = __builtin_nontemporal_load(&flow2[p0]);
    f32x2 fl1 = __builtin_nontemporal_load(&flow2[p1]);

    const f32x4* img4 = (const f32x4*)image;
    f32x4* out4 = (f32x4*)out;

    warp_body(img4, out4, p0, c8, fl0);
    warp_body(img4, out4, p1, c8, fl1);
}

extern "C" void kernel_launch(void* const* d_in, const int* in_sizes, int n_in,
                              void* d_out, int out_size, void* d_ws, size_t ws_size,
                              hipStream_t stream) {
    const float* image = (const float*)d_in[0];
    const float* flow  = (const float*)d_in[1];
    float* out = (float*)d_out;

    backwarp_kernel<<<NBLK, 256, 0, stream>>>(image, flow, out);
}

// Round 6
// 101.846 us; speedup vs baseline: 1.2228x; 1.2228x over previous
//
#include <hip/hip_runtime.h>

// Backwarp (tfa.image.dense_image_warp):
// out[b,y,x,c] = bilinear(image, y - flow[b,y,x,0], x - flow[b,y,x,1])
// floors clamped to [0, size-2], alphas clamped to [0,1].

#define BB 4
#define HH 512
#define WW 512
#define CV 16        // float4 chunks per pixel (C=64)
#define NBLK 16384   // blocks; each covers 64 consecutive pixels (2 px/thread x 32)

typedef float f32x4 __attribute__((ext_vector_type(4)));
typedef float f32x2 __attribute__((ext_vector_type(2)));

__device__ __forceinline__ void addr_alpha(
    long long p, int c8, long long& i00, float& ay, float& ax, f32x2 fl)
{
    int x = (int)(p & (WW - 1));
    long long t = p >> 9;
    int y = (int)(t & (HH - 1));
    int b = (int)(t >> 9);

    float qy = (float)y - fl.x;
    float qx = (float)x - fl.y;
    float fy = fminf(fmaxf(floorf(qy), 0.0f), (float)(HH - 2));
    float fx = fminf(fmaxf(floorf(qx), 0.0f), (float)(WW - 2));
    ay = fminf(fmaxf(qy - fy, 0.0f), 1.0f);
    ax = fminf(fmaxf(qx - fx, 0.0f), 1.0f);
    int y0 = (int)fy;
    int x0 = (int)fx;
    i00 = (((long long)b * HH + y0) * WW + x0) * CV + c8;
}

__global__ __launch_bounds__(256) void backwarp_kernel(
    const float* __restrict__ image,
    const float* __restrict__ flow,
    float* __restrict__ out)
{
    // XCD-bijective swizzle: each XCD gets a contiguous 1/8 slab of the grid
    int bid = (int)blockIdx.x;
    int orig = (bid & 7) * (NBLK / 8) + (bid >> 3);

    long long pix_base = (long long)orig * 64;
    int c8 = (int)(threadIdx.x & 7);   // which pair of float4 chunks
    int pl = (int)(threadIdx.x >> 3);  // pixel lane 0..31
    long long p0 = pix_base + pl;
    long long p1 = pix_base + 32 + pl;

    const f32x2* flow2 = (const f32x2*)flow;
    f32x2 fl0 = __builtin_nontemporal_load(&flow2[p0]);
    f32x2 fl1 = __builtin_nontemporal_load(&flow2[p1]);

    const f32x4* img4 = (const f32x4*)image;
    f32x4* out4 = (f32x4*)out;

    long long i00_0, i00_1;
    float ay0, ax0, ay1, ax1;
    addr_alpha(p0, c8, i00_0, ay0, ax0, fl0);
    addr_alpha(p1, c8, i00_1, ay1, ax1, fl1);

    long long i01_0 = i00_0 + CV;
    long long i10_0 = i00_0 + (long long)WW * CV;
    long long i11_0 = i10_0 + CV;
    long long i01_1 = i00_1 + CV;
    long long i10_1 = i00_1 + (long long)WW * CV;
    long long i11_1 = i10_1 + CV;

    // ---- issue ALL 16 image loads before any compute (MLP) ----
    f32x4 tl0A = img4[i00_0];  f32x4 tl0B = img4[i00_0 + 8];
    f32x4 tr0A = img4[i01_0];  f32x4 tr0B = img4[i01_0 + 8];
    f32x4 bl0A = img4[i10_0];  f32x4 bl0B = img4[i10_0 + 8];
    f32x4 br0A = img4[i11_0];  f32x4 br0B = img4[i11_0 + 8];
    f32x4 tl1A = img4[i00_1];  f32x4 tl1B = img4[i00_1 + 8];
    f32x4 tr1A = img4[i01_1];  f32x4 tr1B = img4[i01_1 + 8];
    f32x4 bl1A = img4[i10_1];  f32x4 bl1B = img4[i10_1 + 8];
    f32x4 br1A = img4[i11_1];  f32x4 br1B = img4[i11_1 + 8];

    // ---- pixel 0: lerp + NT store (frees its 8 corner regs) ----
    {
        f32x4 topA = tl0A + ax0 * (tr0A - tl0A);
        f32x4 botA = bl0A + ax0 * (br0A - bl0A);
        f32x4 rA   = topA + ay0 * (botA - topA);
        f32x4 topB = tl0B + ax0 * (tr0B - tl0B);
        f32x4 botB = bl0B + ax0 * (br0B - bl0B);
        f32x4 rB   = topB + ay0 * (botB - topB);
        long long o = p0 * CV + c8;
        __builtin_nontemporal_store(rA, &out4[o]);      // write-once: bypass L2
        __builtin_nontemporal_store(rB, &out4[o + 8]);
    }

    // ---- pixel 1 ----
    {
        f32x4 topA = tl1A + ax1 * (tr1A - tl1A);
        f32x4 botA = bl1A + ax1 * (br1A - bl1A);
        f32x4 rA   = topA + ay1 * (botA - topA);
        f32x4 topB = tl1B + ax1 * (tr1B - tl1B);
        f32x4 botB = bl1B + ax1 * (br1B - bl1B);
        f32x4 rB   = topB + ay1 * (botB - topB);
        long long o = p1 * CV + c8;
        __builtin_nontemporal_store(rA, &out4[o]);
        __builtin_nontemporal_store(rB, &out4[o + 8]);
    }
}

extern "C" void kernel_launch(void* const* d_in, const int* in_sizes, int n_in,
                              void* d_out, int out_size, void* d_ws, size_t ws_size,
                              hipStream_t stream) {
    const float* image = (const float*)d_in[0];
    const float* flow  = (const float*)d_in[1];
    float* out = (float*)d_out;

    backwarp_kernel<<<NBLK, 256, 0, stream>>>(image, flow, out);
}

// Round 7
// 98.073 us; speedup vs baseline: 1.2698x; 1.0385x over previous
//
#include <hip/hip_runtime.h>

// Backwarp (tfa.image.dense_image_warp):
// out[b,y,x,c] = bilinear(image, y - flow[b,y,x,0], x - flow[b,y,x,1])
// floors clamped to [0, size-2], alphas clamped to [0,1].

#define BB 4
#define HH 512
#define WW 512
#define CV 16        // float4 chunks per pixel (C=64)
#define NBLK 16384   // blocks; each covers 64 consecutive pixels (2 px/thread x 32)

typedef float f32x4 __attribute__((ext_vector_type(4)));
typedef float f32x2 __attribute__((ext_vector_type(2)));

__device__ __forceinline__ void addr_alpha(
    long long p, int c8, long long& i00, float& ay, float& ax, f32x2 fl)
{
    int x = (int)(p & (WW - 1));
    long long t = p >> 9;
    int y = (int)(t & (HH - 1));
    int b = (int)(t >> 9);

    float qy = (float)y - fl.x;
    float qx = (float)x - fl.y;
    float fy = fminf(fmaxf(floorf(qy), 0.0f), (float)(HH - 2));
    float fx = fminf(fmaxf(floorf(qx), 0.0f), (float)(WW - 2));
    ay = fminf(fmaxf(qy - fy, 0.0f), 1.0f);
    ax = fminf(fmaxf(qx - fx, 0.0f), 1.0f);
    int y0 = (int)fy;
    int x0 = (int)fx;
    i00 = (((long long)b * HH + y0) * WW + x0) * CV + c8;
}

__global__ __launch_bounds__(256) void backwarp_kernel(
    const float* __restrict__ image,
    const float* __restrict__ flow,
    float* __restrict__ out)
{
    // XCD-bijective swizzle: each XCD gets a contiguous 1/8 slab of the grid
    int bid = (int)blockIdx.x;
    int orig = (bid & 7) * (NBLK / 8) + (bid >> 3);

    long long pix_base = (long long)orig * 64;
    int c8 = (int)(threadIdx.x & 7);   // which pair of float4 chunks
    int pl = (int)(threadIdx.x >> 3);  // pixel lane 0..31
    long long p0 = pix_base + pl;
    long long p1 = pix_base + 32 + pl;

    const f32x2* flow2 = (const f32x2*)flow;
    f32x2 fl0 = __builtin_nontemporal_load(&flow2[p0]);
    f32x2 fl1 = __builtin_nontemporal_load(&flow2[p1]);

    const f32x4* img4 = (const f32x4*)image;
    f32x4* out4 = (f32x4*)out;

    long long i00_0, i00_1;
    float ay0, ax0, ay1, ax1;
    addr_alpha(p0, c8, i00_0, ay0, ax0, fl0);
    addr_alpha(p1, c8, i00_1, ay1, ax1, fl1);

    long long i01_0 = i00_0 + CV;
    long long i10_0 = i00_0 + (long long)WW * CV;
    long long i11_0 = i10_0 + CV;
    long long i01_1 = i00_1 + CV;
    long long i10_1 = i00_1 + (long long)WW * CV;
    long long i11_1 = i10_1 + CV;

    // ---- issue ALL 16 image loads, then FENCE so the compiler cannot sink
    // them back to their uses (round-6 lesson: without this, VGPR=32 and the
    // schedule is 8 serialized vmcnt(0) waits) ----
    f32x4 tl0A = img4[i00_0];  f32x4 tl0B = img4[i00_0 + 8];
    f32x4 tr0A = img4[i01_0];  f32x4 tr0B = img4[i01_0 + 8];
    f32x4 bl0A = img4[i10_0];  f32x4 bl0B = img4[i10_0 + 8];
    f32x4 br0A = img4[i11_0];  f32x4 br0B = img4[i11_0 + 8];
    f32x4 tl1A = img4[i00_1];  f32x4 tl1B = img4[i00_1 + 8];
    f32x4 tr1A = img4[i01_1];  f32x4 tr1B = img4[i01_1 + 8];
    f32x4 bl1A = img4[i10_1];  f32x4 bl1B = img4[i10_1 + 8];
    f32x4 br1A = img4[i11_1];  f32x4 br1B = img4[i11_1 + 8];
    __builtin_amdgcn_sched_barrier(0);

    // ---- pixel 0: lerp + NT store (waits vmcnt(8), not vmcnt(0)) ----
    {
        f32x4 topA = tl0A + ax0 * (tr0A - tl0A);
        f32x4 botA = bl0A + ax0 * (br0A - bl0A);
        f32x4 rA   = topA + ay0 * (botA - topA);
        f32x4 topB = tl0B + ax0 * (tr0B - tl0B);
        f32x4 botB = bl0B + ax0 * (br0B - bl0B);
        f32x4 rB   = topB + ay0 * (botB - topB);
        long long o = p0 * CV + c8;
        __builtin_nontemporal_store(rA, &out4[o]);      // write-once: bypass L2
        __builtin_nontemporal_store(rB, &out4[o + 8]);
    }

    // ---- pixel 1 ----
    {
        f32x4 topA = tl1A + ax1 * (tr1A - tl1A);
        f32x4 botA = bl1A + ax1 * (br1A - bl1A);
        f32x4 rA   = topA + ay1 * (botA - topA);
        f32x4 topB = tl1B + ax1 * (tr1B - tl1B);
        f32x4 botB = bl1B + ax1 * (br1B - bl1B);
        f32x4 rB   = topB + ay1 * (botB - topB);
        long long o = p1 * CV + c8;
        __builtin_nontemporal_store(rA, &out4[o]);
        __builtin_nontemporal_store(rB, &out4[o + 8]);
    }
}

extern "C" void kernel_launch(void* const* d_in, const int* in_sizes, int n_in,
                              void* d_out, int out_size, void* d_ws, size_t ws_size,
                              hipStream_t stream) {
    const float* image = (const float*)d_in[0];
    const float* flow  = (const float*)d_in[1];
    float* out = (float*)d_out;

    backwarp_kernel<<<NBLK, 256, 0, stream>>>(image, flow, out);
}